// Round 1
// baseline (806.110 us; speedup 1.0000x reference)
//
#include <hip/hip_runtime.h>

// Problem constants (CARAFE, delta=2, kup=5)
constexpr int N_  = 4;
constexpr int C_  = 256;   // input channels
constexpr int H_  = 64;
constexpr int W_  = 64;
constexpr int Cm_ = 64;    // down channels
constexpr int ENC = 100;   // 25*4 encoder outputs
constexpr int K2_ = 25;
constexpr int OC_ = 256;   // output channels
constexpr int HW_ = H_ * W_;       // 4096
constexpr int H2_ = 128, W2_ = 128;

// ---------------- K1: 1x1 down conv  t[n,m,hw] = sum_c x[n,c,hw]*Wd[m,c] + bd[m]
// grid: n(4) * mgroup(8) * hwchunk(16) = 512 blocks, 256 thr; 8 m per thread
__global__ __launch_bounds__(256) void k_down(const float* __restrict__ x,
                                              const float* __restrict__ Wd,
                                              const float* __restrict__ bd,
                                              float* __restrict__ t) {
    int b   = blockIdx.x;
    int hwc = b & 15;
    int mg  = (b >> 4) & 7;
    int n   = b >> 7;
    int hw  = hwc * 256 + threadIdx.x;
    int m0  = mg * 8;
    const float* xp = x + (size_t)n * C_ * HW_ + hw;
    float acc[8];
#pragma unroll
    for (int i = 0; i < 8; i++) acc[i] = bd[m0 + i];
    for (int c = 0; c < C_; c++) {
        float xv = xp[(size_t)c * HW_];
#pragma unroll
        for (int i = 0; i < 8; i++) acc[i] += xv * Wd[(m0 + i) * C_ + c];
    }
#pragma unroll
    for (int i = 0; i < 8; i++) t[((size_t)(n * Cm_ + m0 + i)) * HW_ + hw] = acc[i];
}

// ---------------- K2: 3x3 encoder conv (SAME, zero pad)
// e[n,o,hw] = be[o] + sum_{m,di,dj} t[n,m,h+di-1,w+dj-1]*We[o,m,di,dj]
// grid: n(4) * ogroup(25) * hwchunk(16) = 1600 blocks, 256 thr; 4 o per thread
__global__ __launch_bounds__(256) void k_enc(const float* __restrict__ t,
                                             const float* __restrict__ We,
                                             const float* __restrict__ be,
                                             float* __restrict__ e) {
    int b   = blockIdx.x;
    int hwc = b & 15;
    int og  = (b >> 4) % 25;
    int n   = b / 400;
    int hw  = hwc * 256 + threadIdx.x;
    int h   = hw >> 6, w = hw & 63;
    int o0  = og * 4;
    float acc[4] = {be[o0], be[o0 + 1], be[o0 + 2], be[o0 + 3]};
    const float* tn = t + (size_t)n * Cm_ * HW_;
    for (int m = 0; m < Cm_; m++) {
        const float* tm = tn + (size_t)m * HW_;
#pragma unroll
        for (int di = 0; di < 3; di++) {
            int r = h + di - 1;
            if (r < 0 || r >= H_) continue;
#pragma unroll
            for (int dj = 0; dj < 3; dj++) {
                int cc = w + dj - 1;
                if (cc < 0 || cc >= W_) continue;
                float tv = tm[r * W_ + cc];
#pragma unroll
                for (int i = 0; i < 4; i++)
                    acc[i] += tv * We[((o0 + i) * Cm_ + m) * 9 + di * 3 + dj];
            }
        }
    }
#pragma unroll
    for (int i = 0; i < 4; i++) e[((size_t)(n * ENC + o0 + i)) * HW_ + hw] = acc[i];
}

// ---------------- K3: softmax over the 25 k-channels for each (n, ij, hw)
// kern layout: [(n*HW + hw)*25 + k]*4 + ij  (contiguous 100 floats per base pixel)
__global__ __launch_bounds__(256) void k_softmax(const float* __restrict__ e,
                                                 float* __restrict__ kern) {
    int idx = blockIdx.x * 256 + threadIdx.x;  // 65536 total
    int hw  = idx & 4095;
    int ij  = (idx >> 12) & 3;
    int n   = idx >> 14;
    const float* ep = e + (size_t)n * ENC * HW_ + (size_t)ij * HW_ + hw;
    float v[25];
    float mx = -1e30f;
#pragma unroll
    for (int k = 0; k < 25; k++) {
        v[k] = ep[(size_t)(k * 4) * HW_];
        mx   = fmaxf(mx, v[k]);
    }
    float s = 0.f;
#pragma unroll
    for (int k = 0; k < 25; k++) {
        v[k] = __expf(v[k] - mx);
        s += v[k];
    }
    float inv = 1.0f / s;
    float* kp = kern + ((size_t)(n * HW_ + hw) * K2_) * 4 + ij;
#pragma unroll
    for (int k = 0; k < 25; k++) kp[k * 4] = v[k] * inv;
}

// ---------------- K4: fused reassembly + pixel shuffle + final 1x1 conv
// Block handles (n, h, 16 base w) -> 64 upsampled pixels x 256 output chans.
// Phase1: up[c][p] = sum_k x[n,c,h-2+di,w-2+dj] * kern[n,h,w,k,ij]  (c chunked by 32)
// Phase2: acc[o][p] += sum_c Wout[o][c] * up[c][p]
// grid: n(4)*h(64)*wt(4) = 1024 blocks, 256 thr, 64 fp32 acc/thread
__global__ __launch_bounds__(256) void k_carafe_out(const float* __restrict__ x,
                                                    const float* __restrict__ kern,
                                                    const float* __restrict__ Wo,
                                                    const float* __restrict__ bo,
                                                    float* __restrict__ out) {
    int b  = blockIdx.x;
    int wt = b & 3;
    int h  = (b >> 2) & 63;
    int n  = b >> 8;
    int w0 = wt * 16;
    int tid = threadIdx.x;

    __shared__ __align__(16) float xs[32 * 101];   // [cl][r*20+col], row stride 101 (odd -> no bank conflict)
    __shared__ __align__(16) float kr[16 * 100];   // [wb][k*4+ij]
    __shared__ __align__(16) float upL[64 * 36];   // [p][cl], stride 36 (16B-aligned rows)
    __shared__ __align__(16) float WtL[256 * 32];  // [o][cl]

    // load kern tile (1600 contiguous floats), once
    {
        const float* kb = kern + (size_t)(n * HW_ + h * 64 + w0) * 100;
        for (int l = tid; l < 1600; l += 256) kr[l] = kb[l];
    }

    int cl   = tid & 31;   // phase-1 channel-local
    int pgrp = tid >> 5;   // phase-1 pixel group (8 pixels each)
    int og   = tid >> 6;   // phase-2 o-group (64 o each)
    int p2   = tid & 63;   // phase-2 pixel

    float acc[64];
#pragma unroll
    for (int i = 0; i < 64; i++) acc[i] = 0.f;

    for (int ch = 0; ch < 8; ch++) {
        int c0 = ch * 32;
        __syncthreads();  // previous phase2 done (and kr load on first iter)

        // stage x patch: 32 c x 5 rows x 20 cols (zero pad at borders)
        for (int l = tid; l < 3200; l += 256) {
            int c   = l / 100;
            int rem = l - c * 100;
            int r   = rem / 20;
            int col = rem - r * 20;
            int gr  = h - 2 + r;
            int gc  = w0 - 2 + col;
            float v = 0.f;
            if (gr >= 0 && gr < H_ && gc >= 0 && gc < W_)
                v = x[((size_t)(n * C_ + c0 + c)) * HW_ + gr * 64 + gc];
            xs[c * 101 + r * 20 + col] = v;
        }
        // stage Wout chunk: [o][cl] 256x32
        for (int l = tid; l < 8192; l += 256) {
            int o = l >> 5;
            int c = l & 31;
            WtL[l] = Wo[o * C_ + c0 + c];
        }
        __syncthreads();

        // phase 1: reassembly for this c-chunk
#pragma unroll
        for (int pp = 0; pp < 8; pp++) {
            int p  = pgrp * 8 + pp;
            int i  = p >> 5;
            int xx = p & 31;
            int wb = xx >> 1;
            int j  = xx & 1;
            int ij = i * 2 + j;
            const float* xr  = &xs[cl * 101 + wb];
            const float* krp = &kr[wb * 100 + ij];
            float s = 0.f;
#pragma unroll
            for (int k = 0; k < 25; k++) {
                int di = k / 5, dj = k % 5;
                s += xr[di * 20 + dj] * krp[k * 4];
            }
            upL[p * 36 + cl] = s;
        }
        __syncthreads();

        // phase 2: partial 1x1 GEMM over this c-chunk
        const float4* upv = (const float4*)&upL[p2 * 36];
#pragma unroll
        for (int c4 = 0; c4 < 8; c4++) {
            float4 u = upv[c4];
#pragma unroll
            for (int oo = 0; oo < 64; oo++) {
                const float4 wv = *(const float4*)&WtL[(og * 64 + oo) * 32 + c4 * 4];
                acc[oo] += wv.x * u.x + wv.y * u.y + wv.z * u.z + wv.w * u.w;
            }
        }
    }

    // store: out[n, o, 2h+i, 2*w0+xx]; lanes cover two 128B row segments
    int i  = p2 >> 5;
    int xx = p2 & 31;
    int y  = 2 * h + i;
    int xc = 2 * w0 + xx;
#pragma unroll
    for (int oo = 0; oo < 64; oo++) {
        int o = og * 64 + oo;
        out[((size_t)(n * OC_ + o) * H2_ + y) * W2_ + xc] = acc[oo] + bo[o];
    }
}

extern "C" void kernel_launch(void* const* d_in, const int* in_sizes, int n_in,
                              void* d_out, int out_size, void* d_ws, size_t ws_size,
                              hipStream_t stream) {
    const float* x  = (const float*)d_in[0];
    const float* Wd = (const float*)d_in[1];
    const float* bd = (const float*)d_in[2];
    const float* We = (const float*)d_in[3];
    const float* be = (const float*)d_in[4];
    const float* Wo = (const float*)d_in[5];
    const float* bo = (const float*)d_in[6];
    float* out = (float*)d_out;

    float* ws   = (float*)d_ws;
    float* t    = ws;                       // 4*64*4096      = 1,048,576 floats
    float* e    = t + N_ * Cm_ * HW_;       // 4*100*4096     = 1,638,400 floats
    float* kern = e + N_ * ENC * HW_;       // 4*4096*25*4    = 1,638,400 floats
    // total workspace: 17.3 MB

    k_down<<<512, 256, 0, stream>>>(x, Wd, bd, t);
    k_enc<<<1600, 256, 0, stream>>>(t, We, be, e);
    k_softmax<<<256, 256, 0, stream>>>(e, kern);
    k_carafe_out<<<1024, 256, 0, stream>>>(x, kern, Wo, bo, out);
}

// Round 2
// 326.072 us; speedup vs baseline: 2.4722x; 2.4722x over previous
//
#include <hip/hip_runtime.h>

// Problem constants (CARAFE, delta=2, kup=5)
constexpr int N_  = 4;
constexpr int C_  = 256;   // input channels
constexpr int H_  = 64;
constexpr int W_  = 64;
constexpr int Cm_ = 64;    // down channels
constexpr int ENC = 100;   // 25*4 encoder outputs
constexpr int OC_ = 256;   // output channels
constexpr int HW_ = H_ * W_;       // 4096
constexpr int H2_ = 128, W2_ = 128;

__device__ inline unsigned short f2bf(float f) {
    unsigned int u = __float_as_uint(f);
    unsigned int r = u + 0x7FFFu + ((u >> 16) & 1u);  // RNE
    return (unsigned short)(r >> 16);
}
__device__ inline float bf2f(unsigned short s) {
    return __uint_as_float(((unsigned int)s) << 16);
}

// ---------------- K1: 1x1 down conv  t[n,m,hw] = sum_c x[n,c,hw]*Wd[m,c] + bd[m]
__global__ __launch_bounds__(256) void k_down(const float* __restrict__ x,
                                              const float* __restrict__ Wd,
                                              const float* __restrict__ bd,
                                              float* __restrict__ t) {
    int b   = blockIdx.x;
    int hwc = b & 15;
    int mg  = (b >> 4) & 7;
    int n   = b >> 7;
    int hw  = hwc * 256 + threadIdx.x;
    int m0  = mg * 8;
    const float* xp = x + (size_t)n * C_ * HW_ + hw;
    float acc[8];
#pragma unroll
    for (int i = 0; i < 8; i++) acc[i] = bd[m0 + i];
    for (int c = 0; c < C_; c++) {
        float xv = xp[(size_t)c * HW_];
#pragma unroll
        for (int i = 0; i < 8; i++) acc[i] += xv * Wd[(m0 + i) * C_ + c];
    }
#pragma unroll
    for (int i = 0; i < 8; i++) t[((size_t)(n * Cm_ + m0 + i)) * HW_ + hw] = acc[i];
}

// ---------------- K2: 3x3 encoder conv (SAME, zero pad)
__global__ __launch_bounds__(256) void k_enc(const float* __restrict__ t,
                                             const float* __restrict__ We,
                                             const float* __restrict__ be,
                                             float* __restrict__ e) {
    int b   = blockIdx.x;
    int hwc = b & 15;
    int og  = (b >> 4) % 25;
    int n   = b / 400;
    int hw  = hwc * 256 + threadIdx.x;
    int h   = hw >> 6, w = hw & 63;
    int o0  = og * 4;
    float acc[4] = {be[o0], be[o0 + 1], be[o0 + 2], be[o0 + 3]};
    const float* tn = t + (size_t)n * Cm_ * HW_;
    for (int m = 0; m < Cm_; m++) {
        const float* tm = tn + (size_t)m * HW_;
#pragma unroll
        for (int di = 0; di < 3; di++) {
            int r = h + di - 1;
            if (r < 0 || r >= H_) continue;
#pragma unroll
            for (int dj = 0; dj < 3; dj++) {
                int cc = w + dj - 1;
                if (cc < 0 || cc >= W_) continue;
                float tv = tm[r * W_ + cc];
#pragma unroll
                for (int i = 0; i < 4; i++)
                    acc[i] += tv * We[((o0 + i) * Cm_ + m) * 9 + di * 3 + dj];
            }
        }
    }
#pragma unroll
    for (int i = 0; i < 4; i++) e[((size_t)(n * ENC + o0 + i)) * HW_ + hw] = acc[i];
}

// ---------------- K3: softmax over 25 k-channels, write kern2[n][h][k][ij][w]
__global__ __launch_bounds__(256) void k_softmax(const float* __restrict__ e,
                                                 float* __restrict__ kern2) {
    int idx = blockIdx.x * 256 + threadIdx.x;  // 65536 total
    int hw  = idx & 4095;
    int ij  = (idx >> 12) & 3;
    int n   = idx >> 14;
    int h   = hw >> 6, w = hw & 63;
    const float* ep = e + (size_t)n * ENC * HW_ + (size_t)ij * HW_ + hw;
    float v[25];
    float mx = -1e30f;
#pragma unroll
    for (int k = 0; k < 25; k++) {
        v[k] = ep[(size_t)(k * 4) * HW_];
        mx   = fmaxf(mx, v[k]);
    }
    float s = 0.f;
#pragma unroll
    for (int k = 0; k < 25; k++) {
        v[k] = __expf(v[k] - mx);
        s += v[k];
    }
    float inv = 1.0f / s;
    // kern2 index: (n*64+h)*6400 + k*256 + ij*64 + w   (coalesced across w per store)
    float* kp = kern2 + (size_t)(n * 64 + h) * 6400 + ij * 64 + w;
#pragma unroll
    for (int k = 0; k < 25; k++) kp[k * 256] = v[k] * inv;
}

// ---------------- K4: y1 = Wo . x  (GEMM 256o x 16384pix x 256c), bf16 out
// block: 64 o x 128 pix, thread: 8 o x 4 pix (32 acc); K chunked by 32 via LDS
__global__ __launch_bounds__(256) void k_y1(const float* __restrict__ x,
                                            const float* __restrict__ Wo,
                                            unsigned short* __restrict__ y1b) {
    int b  = blockIdx.x;           // 4 n * 4 og * 32 pt = 512
    int pt = b & 31;
    int og = (b >> 5) & 3;
    int n  = b >> 7;
    int p0 = pt * 128;
    int o0 = og * 64;
    int tid = threadIdx.x;
    int og8 = tid >> 5;    // 8 groups of 8 o
    int pg  = tid & 31;    // 32 groups of 4 pix

    __shared__ __align__(16) float xs[32 * 128];   // 16 KB
    __shared__ __align__(16) float ws[64 * 33];    // 8.4 KB (pad 33 vs bank conflicts)

    float acc[8][4];
#pragma unroll
    for (int j = 0; j < 8; j++)
#pragma unroll
        for (int q = 0; q < 4; q++) acc[j][q] = 0.f;

    const float* xb = x + (size_t)n * C_ * HW_ + p0;
    for (int kc = 0; kc < 8; kc++) {
        int c0 = kc * 32;
        __syncthreads();
#pragma unroll
        for (int i = 0; i < 4; i++) {       // stage x chunk 32c x 128pix
            int idx4 = i * 256 + tid;
            int c    = idx4 >> 5;
            int p4   = (idx4 & 31) * 4;
            *(float4*)&xs[c * 128 + p4] = *(const float4*)&xb[(size_t)(c0 + c) * HW_ + p4];
        }
#pragma unroll
        for (int i = 0; i < 8; i++) {       // stage Wo chunk 64o x 32c
            int idx = i * 256 + tid;
            int o = idx >> 5, c = idx & 31;
            ws[o * 33 + c] = Wo[(o0 + o) * C_ + c0 + c];
        }
        __syncthreads();
#pragma unroll
        for (int k = 0; k < 32; k++) {
            float4 xv = *(float4*)&xs[k * 128 + pg * 4];
#pragma unroll
            for (int j = 0; j < 8; j++) {
                float wv = ws[(og8 * 8 + j) * 33 + k];
                acc[j][0] += wv * xv.x; acc[j][1] += wv * xv.y;
                acc[j][2] += wv * xv.z; acc[j][3] += wv * xv.w;
            }
        }
    }
#pragma unroll
    for (int j = 0; j < 8; j++) {
        int o = o0 + og8 * 8 + j;
        ushort4 pk;
        pk.x = f2bf(acc[j][0]); pk.y = f2bf(acc[j][1]);
        pk.z = f2bf(acc[j][2]); pk.w = f2bf(acc[j][3]);
        *(ushort4*)&y1b[((size_t)(n * OC_ + o)) * HW_ + p0 + pg * 4] = pk;
    }
}

// ---------------- K5: reassembly at base resolution + pixel shuffle + bias
// out[n,o,2h+i,2w+j] = sum_k kern2[n,h,k,ij,w] * y1[n,o,h+di-2,w+dj-2] + bo[o]
// block: (n, og of 16 o, strip of 4 h rows); thread: (w, 4 o), 16 acc per row
__global__ __launch_bounds__(256) void k_reasm(const unsigned short* __restrict__ y1b,
                                               const float* __restrict__ kern2,
                                               const float* __restrict__ bo,
                                               float* __restrict__ out) {
    int b  = blockIdx.x;           // 4 n * 16 og * 16 hs = 1024
    int hs = b & 15;
    int og = (b >> 4) & 15;
    int n  = b >> 8;
    int h0 = hs * 4;
    int o0 = og * 16;
    int tid = threadIdx.x;
    int w  = tid & 63;
    int ol = tid >> 6;             // 4 groups of 4 o

    __shared__ float ys[16 * 8 * 68];   // 34.8 KB: [o][r][c], c = gc+2

    const unsigned short* yb = y1b + ((size_t)(n * OC_ + o0)) * HW_;
    // pass A: 128 (o,r) rows x cols 0..63  (coalesced: one row per wave)
#pragma unroll
    for (int i = 0; i < 32; i++) {
        int idx = i * 256 + tid;
        int row = idx >> 6;        // o*8 + r
        int c   = idx & 63;
        int o   = row >> 3, r = row & 7;
        int gr  = h0 + r - 2, gc = c - 2;
        float v = 0.f;
        if (gr >= 0 && gr < H_ && gc >= 0)
            v = bf2f(yb[(size_t)o * HW_ + gr * W_ + gc]);
        ys[row * 68 + c] = v;
    }
    // pass B: cols 64..67
#pragma unroll
    for (int i = 0; i < 2; i++) {
        int idx = i * 256 + tid;
        int row = idx >> 2;
        int c   = 64 + (idx & 3);
        int o   = row >> 3, r = row & 7;
        int gr  = h0 + r - 2, gc = c - 2;
        float v = 0.f;
        if (gr >= 0 && gr < H_ && gc < W_)
            v = bf2f(yb[(size_t)o * HW_ + gr * W_ + gc]);
        ys[row * 68 + c] = v;
    }
    __syncthreads();

    float bias[4];
#pragma unroll
    for (int oo = 0; oo < 4; oo++) bias[oo] = bo[o0 + ol * 4 + oo];

    const float* kb = kern2 + (size_t)(n * 64) * 6400 + w;
    for (int r = 0; r < 4; r++) {
        int h = h0 + r;
        float acc[4][4];
#pragma unroll
        for (int oo = 0; oo < 4; oo++)
#pragma unroll
            for (int q = 0; q < 4; q++) acc[oo][q] = 0.f;
        const float* kr = kb + (size_t)h * 6400;
#pragma unroll
        for (int k = 0; k < 25; k++) {
            float kv0 = kr[k * 256];
            float kv1 = kr[k * 256 + 64];
            float kv2 = kr[k * 256 + 128];
            float kv3 = kr[k * 256 + 192];
            int di = k / 5, dj = k % 5;
#pragma unroll
            for (int oo = 0; oo < 4; oo++) {
                float yv = ys[((ol * 4 + oo) * 8 + r + di) * 68 + w + dj];
                acc[oo][0] += kv0 * yv; acc[oo][1] += kv1 * yv;
                acc[oo][2] += kv2 * yv; acc[oo][3] += kv3 * yv;
            }
        }
#pragma unroll
        for (int oo = 0; oo < 4; oo++) {
            int o = o0 + ol * 4 + oo;
#pragma unroll
            for (int i = 0; i < 2; i++) {
                float2 v = make_float2(acc[oo][i * 2 + 0] + bias[oo],
                                       acc[oo][i * 2 + 1] + bias[oo]);
                *(float2*)&out[(((size_t)(n * OC_ + o)) * H2_ + (2 * h + i)) * W2_ + 2 * w] = v;
            }
        }
    }
}

extern "C" void kernel_launch(void* const* d_in, const int* in_sizes, int n_in,
                              void* d_out, int out_size, void* d_ws, size_t ws_size,
                              hipStream_t stream) {
    const float* x  = (const float*)d_in[0];
    const float* Wd = (const float*)d_in[1];
    const float* bd = (const float*)d_in[2];
    const float* We = (const float*)d_in[3];
    const float* be = (const float*)d_in[4];
    const float* Wo = (const float*)d_in[5];
    const float* bo = (const float*)d_in[6];
    float* out = (float*)d_out;

    float* ws    = (float*)d_ws;
    float* t     = ws;                      // 1,048,576 fl
    float* e     = t + N_ * Cm_ * HW_;      // 1,638,400 fl
    float* kern2 = e + N_ * ENC * HW_;      // 1,638,400 fl -> total 17.3 MB
    // y1 (bf16, 8.4 MB) aliases the dead t+e region (10.7 MB) after softmax
    unsigned short* y1b = (unsigned short*)d_ws;

    k_down<<<512, 256, 0, stream>>>(x, Wd, bd, t);
    k_enc<<<1600, 256, 0, stream>>>(t, We, be, e);
    k_softmax<<<256, 256, 0, stream>>>(e, kern2);
    k_y1<<<512, 256, 0, stream>>>(x, Wo, y1b);
    k_reasm<<<1024, 256, 0, stream>>>(y1b, kern2, bo, out);
}

// Round 3
// 203.973 us; speedup vs baseline: 3.9520x; 1.5986x over previous
//
#include <hip/hip_runtime.h>

// Problem constants (CARAFE, delta=2, kup=5)
constexpr int N_  = 4;
constexpr int C_  = 256;
constexpr int H_  = 64;
constexpr int W_  = 64;
constexpr int Cm_ = 64;
constexpr int ENC = 100;
constexpr int OC_ = 256;
constexpr int HW_ = H_ * W_;       // 4096
constexpr int H2_ = 128, W2_ = 128;

typedef float  f32x16 __attribute__((ext_vector_type(16)));
typedef short  s16x8  __attribute__((ext_vector_type(8)));

__device__ inline unsigned short f2bf(float f) {
    unsigned int u = __float_as_uint(f);
    unsigned int r = u + 0x7FFFu + ((u >> 16) & 1u);  // RNE
    return (unsigned short)(r >> 16);
}
__device__ inline float bf2f(unsigned short s) {
    return __uint_as_float(((unsigned int)s) << 16);
}

// ---------------- prep: We (100,64,3,3) fp32 -> Web[tap][128 o][64 m] bf16 (o>=100 zero)
__global__ __launch_bounds__(256) void k_wprep(const float* __restrict__ We,
                                               unsigned short* __restrict__ Web) {
    int idx = blockIdx.x * 256 + threadIdx.x;     // 9*128*64 = 73728
    int tap = idx >> 13;
    int rem = idx & 8191;
    int o   = rem >> 6;
    int m   = rem & 63;
    Web[idx] = (o < ENC) ? f2bf(We[(o * Cm_ + m) * 9 + tap]) : (unsigned short)0;
}

// ---------------- prep: Wo (256,256) fp32 -> bf16
__global__ __launch_bounds__(256) void k_woprep(const float* __restrict__ Wo,
                                                unsigned short* __restrict__ Wob) {
    int idx = blockIdx.x * 256 + threadIdx.x;     // 65536
    Wob[idx] = f2bf(Wo[idx]);
}

// ---------------- K1: 1x1 down conv -> t2 bf16 [n][hw][64 m]
__global__ __launch_bounds__(256) void k_down(const float* __restrict__ x,
                                              const float* __restrict__ Wd,
                                              const float* __restrict__ bd,
                                              unsigned short* __restrict__ t2) {
    int b   = blockIdx.x;
    int hwc = b & 15;
    int mg  = (b >> 4) & 7;
    int n   = b >> 7;
    int hw  = hwc * 256 + threadIdx.x;
    int m0  = mg * 8;
    const float* xp = x + (size_t)n * C_ * HW_ + hw;
    float acc[8];
#pragma unroll
    for (int i = 0; i < 8; i++) acc[i] = bd[m0 + i];
    for (int c = 0; c < C_; c++) {
        float xv = xp[(size_t)c * HW_];
#pragma unroll
        for (int i = 0; i < 8; i++) acc[i] += xv * Wd[(m0 + i) * C_ + c];
    }
    ushort4 pa, pb;
    pa.x = f2bf(acc[0]); pa.y = f2bf(acc[1]); pa.z = f2bf(acc[2]); pa.w = f2bf(acc[3]);
    pb.x = f2bf(acc[4]); pb.y = f2bf(acc[5]); pb.z = f2bf(acc[6]); pb.w = f2bf(acc[7]);
    size_t base = ((size_t)(n * HW_ + hw)) * 64 + m0;
    *(ushort4*)&t2[base]     = pa;
    *(ushort4*)&t2[base + 4] = pb;
}

// ---------------- K2: 3x3 encoder conv via MFMA 32x32x16 bf16
// block: (n, h, o-tile of 32); 128 thr = 2 waves (one per 32-pixel group)
// D[m=o][n=pix] += sum_{tap,k} Web[tap][o][k] * t[k][pix+off(tap)]
__global__ __launch_bounds__(128) void k_enc(const unsigned short* __restrict__ t2,
                                             const unsigned short* __restrict__ Web,
                                             const float* __restrict__ be,
                                             float* __restrict__ e) {
    int b  = blockIdx.x;              // 4 ot * 64 h * 4 n = 1024 (ot fastest)
    int ot = b & 3;
    int h  = (b >> 2) & 63;
    int n  = b >> 8;
    int o0 = ot * 32;
    int tid  = threadIdx.x;
    int lane = tid & 63;
    int pg   = tid >> 6;              // wave id = pixel group

    __shared__ unsigned short ts[3 * 66 * 68];   // [r][cw][m pad 68] = 26.9 KB

    // stage t rows h-1..h+1, cols -1..64 (zero-pad), 64 m each
    for (int idx = tid; idx < 3 * 66 * 8; idx += 128) {
        int r   = idx / (66 * 8);
        int rem = idx - r * (66 * 8);
        int cw  = rem >> 3;
        int mc  = rem & 7;
        int gh  = h - 1 + r;
        int gw  = cw - 1;
        uint2 lo = make_uint2(0u, 0u), hi = make_uint2(0u, 0u);
        if (gh >= 0 && gh < H_ && gw >= 0 && gw < W_) {
            uint4 v = *(const uint4*)&t2[((size_t)(n * HW_ + gh * W_ + gw)) * 64 + mc * 8];
            lo = make_uint2(v.x, v.y); hi = make_uint2(v.z, v.w);
        }
        int la = (r * 66 + cw) * 68 + mc * 8;
        *(uint2*)&ts[la]     = lo;
        *(uint2*)&ts[la + 4] = hi;
    }
    __syncthreads();

    f32x16 acc;
#pragma unroll
    for (int i = 0; i < 16; i++) acc[i] = 0.f;

    int oL   = lane & 31;             // o within tile (A rows)
    int half = lane >> 5;             // k-half selector
    const unsigned short* wb = Web + ((size_t)(o0 + oL)) * 64 + half * 8;

    s16x8 wf[2][4];
    // prefetch tap 0 A-fragments
#pragma unroll
    for (int kc = 0; kc < 4; kc++)
        *(uint4*)&wf[0][kc] = *(const uint4*)&wb[kc * 16];

    for (int tap = 0; tap < 9; tap++) {
        int cur = tap & 1;
        if (tap < 8) {
            const unsigned short* wn = wb + (size_t)(tap + 1) * 128 * 64;
#pragma unroll
            for (int kc = 0; kc < 4; kc++)
                *(uint4*)&wf[cur ^ 1][kc] = *(const uint4*)&wn[kc * 16];
        }
        int di = tap / 3, dj = tap % 3;
        int cw = pg * 32 + (lane & 31) + dj;          // B col (pixel + halo offset)
        const unsigned short* tb = &ts[(di * 66 + cw) * 68 + half * 8];
#pragma unroll
        for (int kc = 0; kc < 4; kc++) {
            s16x8 bf;
            ((uint2*)&bf)[0] = *(const uint2*)&tb[kc * 16];
            ((uint2*)&bf)[1] = *(const uint2*)&tb[kc * 16 + 4];
            acc = __builtin_amdgcn_mfma_f32_32x32x16_bf16(wf[cur][kc], bf, acc, 0, 0, 0);
        }
    }

    // epilogue: e[n][o][hw] (+bias), skip padded o
    int col = lane & 31;
    int pix = h * 64 + pg * 32 + col;
#pragma unroll
    for (int r = 0; r < 16; r++) {
        int o = o0 + (r & 3) + 8 * (r >> 2) + 4 * half;
        if (o < ENC)
            e[((size_t)(n * ENC + o)) * HW_ + pix] = acc[r] + be[o];
    }
}

// ---------------- K3: softmax over 25 k-channels, write kern2[n][h][k][ij][w]
__global__ __launch_bounds__(256) void k_softmax(const float* __restrict__ e,
                                                 float* __restrict__ kern2) {
    int idx = blockIdx.x * 256 + threadIdx.x;  // 65536 total
    int hw  = idx & 4095;
    int ij  = (idx >> 12) & 3;
    int n   = idx >> 14;
    int h   = hw >> 6, w = hw & 63;
    const float* ep = e + (size_t)n * ENC * HW_ + (size_t)ij * HW_ + hw;
    float v[25];
    float mx = -1e30f;
#pragma unroll
    for (int k = 0; k < 25; k++) {
        v[k] = ep[(size_t)(k * 4) * HW_];
        mx   = fmaxf(mx, v[k]);
    }
    float s = 0.f;
#pragma unroll
    for (int k = 0; k < 25; k++) {
        v[k] = __expf(v[k] - mx);
        s += v[k];
    }
    float inv = 1.0f / s;
    float* kp = kern2 + (size_t)(n * 64 + h) * 6400 + ij * 64 + w;
#pragma unroll
    for (int k = 0; k < 25; k++) kp[k * 256] = v[k] * inv;
}

// ---------------- K4: y1 = Wo . x via MFMA (bf16), y1 bf16 [n][o][hw]
// block: (n, h, o-tile of 32); 128 thr = 2 waves (one per 32-pixel group)
__global__ __launch_bounds__(128) void k_y1(const float* __restrict__ x,
                                            const unsigned short* __restrict__ Wob,
                                            unsigned short* __restrict__ y1b) {
    int b  = blockIdx.x;              // 8 ot * 64 h * 4 n = 2048 (ot fastest)
    int ot = b & 7;
    int h  = (b >> 3) & 63;
    int n  = b >> 9;
    int o0 = ot * 32;
    int tid  = threadIdx.x;
    int lane = tid & 63;
    int pg   = tid >> 6;

    __shared__ unsigned short xs[64 * 260];   // [pix][c pad 260] = 33.3 KB

    // stage + transpose + bf16-convert one 64-pixel row of x (all 256 c)
    const float* xr = x + (size_t)n * C_ * HW_ + h * 64;
    for (int idx = tid; idx < 4096; idx += 128) {
        int c  = idx >> 4;
        int ch = idx & 15;
        float4 v = *(const float4*)&xr[(size_t)c * HW_ + ch * 4];
        int p = ch * 4;
        xs[(p + 0) * 260 + c] = f2bf(v.x);
        xs[(p + 1) * 260 + c] = f2bf(v.y);
        xs[(p + 2) * 260 + c] = f2bf(v.z);
        xs[(p + 3) * 260 + c] = f2bf(v.w);
    }
    __syncthreads();

    f32x16 acc;
#pragma unroll
    for (int i = 0; i < 16; i++) acc[i] = 0.f;

    int oL   = lane & 31;
    int half = lane >> 5;
    const unsigned short* wb = Wob + ((size_t)(o0 + oL)) * C_ + half * 8;
    const unsigned short* tb = &xs[(pg * 32 + (lane & 31)) * 260 + half * 8];

    s16x8 wf[2];
    *(uint4*)&wf[0] = *(const uint4*)&wb[0];
    for (int kc = 0; kc < 16; kc++) {
        int cur = kc & 1;
        if (kc < 15)
            *(uint4*)&wf[cur ^ 1] = *(const uint4*)&wb[(kc + 1) * 16];
        s16x8 bf;
        ((uint2*)&bf)[0] = *(const uint2*)&tb[kc * 16];
        ((uint2*)&bf)[1] = *(const uint2*)&tb[kc * 16 + 4];
        acc = __builtin_amdgcn_mfma_f32_32x32x16_bf16(wf[cur], bf, acc, 0, 0, 0);
    }

    int col = lane & 31;
    int pix = h * 64 + pg * 32 + col;
#pragma unroll
    for (int r = 0; r < 16; r++) {
        int o = o0 + (r & 3) + 8 * (r >> 2) + 4 * half;
        y1b[((size_t)(n * OC_ + o)) * HW_ + pix] = f2bf(acc[r]);
    }
}

// ---------------- K5: reassembly at base resolution + pixel shuffle + bias
__global__ __launch_bounds__(256) void k_reasm(const unsigned short* __restrict__ y1b,
                                               const float* __restrict__ kern2,
                                               const float* __restrict__ bo,
                                               float* __restrict__ out) {
    int b  = blockIdx.x;           // 4 n * 16 og * 16 hs = 1024
    int hs = b & 15;
    int og = (b >> 4) & 15;
    int n  = b >> 8;
    int h0 = hs * 4;
    int o0 = og * 16;
    int tid = threadIdx.x;
    int w  = tid & 63;
    int ol = tid >> 6;             // 4 groups of 4 o

    __shared__ float ys[16 * 8 * 68];   // 34.8 KB

    const unsigned short* yb = y1b + ((size_t)(n * OC_ + o0)) * HW_;
#pragma unroll
    for (int i = 0; i < 32; i++) {
        int idx = i * 256 + tid;
        int row = idx >> 6;
        int c   = idx & 63;
        int o   = row >> 3, r = row & 7;
        int gr  = h0 + r - 2, gc = c - 2;
        float v = 0.f;
        if (gr >= 0 && gr < H_ && gc >= 0)
            v = bf2f(yb[(size_t)o * HW_ + gr * W_ + gc]);
        ys[row * 68 + c] = v;
    }
#pragma unroll
    for (int i = 0; i < 2; i++) {
        int idx = i * 256 + tid;
        int row = idx >> 2;
        int c   = 64 + (idx & 3);
        int o   = row >> 3, r = row & 7;
        int gr  = h0 + r - 2, gc = c - 2;
        float v = 0.f;
        if (gr >= 0 && gr < H_ && gc < W_)
            v = bf2f(yb[(size_t)o * HW_ + gr * W_ + gc]);
        ys[row * 68 + c] = v;
    }
    __syncthreads();

    float bias[4];
#pragma unroll
    for (int oo = 0; oo < 4; oo++) bias[oo] = bo[o0 + ol * 4 + oo];

    const float* kb = kern2 + (size_t)(n * 64) * 6400 + w;
    for (int r = 0; r < 4; r++) {
        int h = h0 + r;
        float acc[4][4];
#pragma unroll
        for (int oo = 0; oo < 4; oo++)
#pragma unroll
            for (int q = 0; q < 4; q++) acc[oo][q] = 0.f;
        const float* kr = kb + (size_t)h * 6400;
#pragma unroll
        for (int k = 0; k < 25; k++) {
            float kv0 = kr[k * 256];
            float kv1 = kr[k * 256 + 64];
            float kv2 = kr[k * 256 + 128];
            float kv3 = kr[k * 256 + 192];
            int di = k / 5, dj = k % 5;
#pragma unroll
            for (int oo = 0; oo < 4; oo++) {
                float yv = ys[((ol * 4 + oo) * 8 + r + di) * 68 + w + dj];
                acc[oo][0] += kv0 * yv; acc[oo][1] += kv1 * yv;
                acc[oo][2] += kv2 * yv; acc[oo][3] += kv3 * yv;
            }
        }
#pragma unroll
        for (int oo = 0; oo < 4; oo++) {
            int o = o0 + ol * 4 + oo;
#pragma unroll
            for (int i = 0; i < 2; i++) {
                float2 v = make_float2(acc[oo][i * 2 + 0] + bias[oo],
                                       acc[oo][i * 2 + 1] + bias[oo]);
                *(float2*)&out[(((size_t)(n * OC_ + o)) * H2_ + (2 * h + i)) * W2_ + 2 * w] = v;
            }
        }
    }
}

extern "C" void kernel_launch(void* const* d_in, const int* in_sizes, int n_in,
                              void* d_out, int out_size, void* d_ws, size_t ws_size,
                              hipStream_t stream) {
    const float* x  = (const float*)d_in[0];
    const float* Wd = (const float*)d_in[1];
    const float* bd = (const float*)d_in[2];
    const float* We = (const float*)d_in[3];
    const float* be = (const float*)d_in[4];
    const float* Wo = (const float*)d_in[5];
    const float* bo = (const float*)d_in[6];
    float* out = (float*)d_out;

    // workspace layout (bytes):
    // region A [0 .. 8,650,752): t2 bf16 (2 MB) + e fp32 (6.55 MB);
    //                            later y1b bf16 (8.39 MB) aliases it
    // kern2 fp32 at 8,650,752 (6.55 MB); Web at 15,204,352; Wob at 15,499,264
    char* wsb = (char*)d_ws;
    unsigned short* t2   = (unsigned short*)wsb;
    float*          e    = (float*)(wsb + 2097152);
    unsigned short* y1b  = (unsigned short*)wsb;
    float*          kern2= (float*)(wsb + 8650752);
    unsigned short* Web  = (unsigned short*)(wsb + 15204352);
    unsigned short* Wob  = (unsigned short*)(wsb + 15499264);

    k_wprep  <<<288, 256, 0, stream>>>(We, Web);
    k_woprep <<<256, 256, 0, stream>>>(Wo, Wob);
    k_down   <<<512, 256, 0, stream>>>(x, Wd, bd, t2);
    k_enc    <<<1024, 128, 0, stream>>>(t2, Web, be, e);
    k_softmax<<<256, 256, 0, stream>>>(e, kern2);
    k_y1     <<<2048, 128, 0, stream>>>(x, Wob, y1b);
    k_reasm  <<<1024, 256, 0, stream>>>(y1b, kern2, bo, out);
}

// Round 4
// 203.148 us; speedup vs baseline: 3.9681x; 1.0041x over previous
//
#include <hip/hip_runtime.h>

// Problem constants (CARAFE, delta=2, kup=5)
constexpr int N_  = 4;
constexpr int C_  = 256;
constexpr int H_  = 64;
constexpr int W_  = 64;
constexpr int Cm_ = 64;
constexpr int ENC = 100;
constexpr int OC_ = 256;
constexpr int HW_ = H_ * W_;       // 4096
constexpr int H2_ = 128, W2_ = 128;

typedef float  f32x16 __attribute__((ext_vector_type(16)));
typedef short  s16x8  __attribute__((ext_vector_type(8)));

__device__ inline unsigned short f2bf(float f) {
    unsigned int u = __float_as_uint(f);
    unsigned int r = u + 0x7FFFu + ((u >> 16) & 1u);  // RNE
    return (unsigned short)(r >> 16);
}
__device__ inline float bf2f(unsigned short s) {
    return __uint_as_float(((unsigned int)s) << 16);
}

// ---------------- prep: Wcat = [Wo(256,256); Wd(64,256)] -> bf16 [320][256]
__global__ __launch_bounds__(256) void k_wcat(const float* __restrict__ Wo,
                                              const float* __restrict__ Wd,
                                              unsigned short* __restrict__ Wcat) {
    int idx = blockIdx.x * 256 + threadIdx.x;     // 81920
    int row = idx >> 8, c = idx & 255;
    float v = (row < 256) ? Wo[idx] : Wd[(row - 256) * 256 + c];
    Wcat[idx] = f2bf(v);
}

// ---------------- prep: We (100,64,3,3) fp32 -> Web[tap][128 o][64 m] bf16
__global__ __launch_bounds__(256) void k_wprep(const float* __restrict__ We,
                                               unsigned short* __restrict__ Web) {
    int idx = blockIdx.x * 256 + threadIdx.x;     // 9*128*64 = 73728
    int tap = idx >> 13;
    int rem = idx & 8191;
    int o   = rem >> 6;
    int m   = rem & 63;
    Web[idx] = (o < ENC) ? f2bf(We[(o * Cm_ + m) * 9 + tap]) : (unsigned short)0;
}

// ---------------- K1: fused {y1 = Wo.x} and {t = Wd.x + bd} via MFMA
// block: (n, h, ot of 64 rows); 256 thr = 4 waves (2 o-halves x 2 pixel-halves)
__global__ __launch_bounds__(256) void k_gemm(const float* __restrict__ x,
                                              const unsigned short* __restrict__ Wcat,
                                              const float* __restrict__ bd,
                                              unsigned short* __restrict__ y1b,
                                              unsigned short* __restrict__ t2) {
    int b   = blockIdx.x;              // 5 ot * 64 h * 4 n = 1280
    int ot  = b % 5;
    int rem = b / 5;
    int h   = rem & 63;
    int n   = rem >> 6;
    int o0  = ot * 64;
    int tid  = threadIdx.x;
    int lane = tid & 63;
    int wv   = tid >> 6;
    int og2  = wv & 1;                 // o half within 64-tile
    int pg   = wv >> 1;                // pixel half

    __shared__ unsigned short xs[64 * 260];   // [pix][c pad 260] = 33.3 KB

    // stage + transpose + bf16-convert one 64-pixel row of x (all 256 c)
    const float* xr = x + (size_t)n * C_ * HW_ + h * 64;
    for (int idx = tid; idx < 4096; idx += 256) {
        int c  = idx >> 4;
        int ch = idx & 15;
        float4 v = *(const float4*)&xr[(size_t)c * HW_ + ch * 4];
        int p = ch * 4;
        xs[(p + 0) * 260 + c] = f2bf(v.x);
        xs[(p + 1) * 260 + c] = f2bf(v.y);
        xs[(p + 2) * 260 + c] = f2bf(v.z);
        xs[(p + 3) * 260 + c] = f2bf(v.w);
    }
    __syncthreads();

    f32x16 acc;
#pragma unroll
    for (int i = 0; i < 16; i++) acc[i] = 0.f;

    int oL   = og2 * 32 + (lane & 31);
    int half = lane >> 5;
    const unsigned short* wb = Wcat + ((size_t)(o0 + oL)) * C_ + half * 8;
    const unsigned short* tb = &xs[(pg * 32 + (lane & 31)) * 260 + half * 8];

    s16x8 wf[2];
    *(uint4*)&wf[0] = *(const uint4*)&wb[0];
    for (int kc = 0; kc < 16; kc++) {
        int cur = kc & 1;
        if (kc < 15)
            *(uint4*)&wf[cur ^ 1] = *(const uint4*)&wb[(kc + 1) * 16];
        s16x8 bfv;
        ((uint2*)&bfv)[0] = *(const uint2*)&tb[kc * 16];
        ((uint2*)&bfv)[1] = *(const uint2*)&tb[kc * 16 + 4];
        acc = __builtin_amdgcn_mfma_f32_32x32x16_bf16(wf[cur], bfv, acc, 0, 0, 0);
    }

    int col = lane & 31;
    int pix = h * 64 + pg * 32 + col;
    if (ot < 4) {
#pragma unroll
        for (int r = 0; r < 16; r++) {
            int o = o0 + og2 * 32 + (r & 3) + 8 * (r >> 2) + 4 * half;
            y1b[((size_t)(n * OC_ + o)) * HW_ + pix] = f2bf(acc[r]);
        }
    } else {
#pragma unroll
        for (int r = 0; r < 16; r++) {
            int m = og2 * 32 + (r & 3) + 8 * (r >> 2) + 4 * half;
            t2[((size_t)(n * HW_ + pix)) * 64 + m] = f2bf(acc[r] + bd[m]);
        }
    }
}

// ---------------- K2: 3x3 encoder conv via MFMA 32x32x16 bf16 -> e bf16
__global__ __launch_bounds__(128) void k_enc(const unsigned short* __restrict__ t2,
                                             const unsigned short* __restrict__ Web,
                                             const float* __restrict__ be,
                                             unsigned short* __restrict__ e_bf) {
    int b  = blockIdx.x;              // 4 ot * 64 h * 4 n = 1024
    int ot = b & 3;
    int h  = (b >> 2) & 63;
    int n  = b >> 8;
    int o0 = ot * 32;
    int tid  = threadIdx.x;
    int lane = tid & 63;
    int pg   = tid >> 6;

    __shared__ unsigned short ts[3 * 66 * 68];   // 26.9 KB

    for (int idx = tid; idx < 3 * 66 * 8; idx += 128) {
        int r   = idx / (66 * 8);
        int rem = idx - r * (66 * 8);
        int cw  = rem >> 3;
        int mc  = rem & 7;
        int gh  = h - 1 + r;
        int gw  = cw - 1;
        uint2 lo = make_uint2(0u, 0u), hi = make_uint2(0u, 0u);
        if (gh >= 0 && gh < H_ && gw >= 0 && gw < W_) {
            uint4 v = *(const uint4*)&t2[((size_t)(n * HW_ + gh * W_ + gw)) * 64 + mc * 8];
            lo = make_uint2(v.x, v.y); hi = make_uint2(v.z, v.w);
        }
        int la = (r * 66 + cw) * 68 + mc * 8;
        *(uint2*)&ts[la]     = lo;
        *(uint2*)&ts[la + 4] = hi;
    }
    __syncthreads();

    f32x16 acc;
#pragma unroll
    for (int i = 0; i < 16; i++) acc[i] = 0.f;

    int oL   = lane & 31;
    int half = lane >> 5;
    const unsigned short* wb = Web + ((size_t)(o0 + oL)) * 64 + half * 8;

    s16x8 wf[2][4];
#pragma unroll
    for (int kc = 0; kc < 4; kc++)
        *(uint4*)&wf[0][kc] = *(const uint4*)&wb[kc * 16];

    for (int tap = 0; tap < 9; tap++) {
        int cur = tap & 1;
        if (tap < 8) {
            const unsigned short* wn = wb + (size_t)(tap + 1) * 128 * 64;
#pragma unroll
            for (int kc = 0; kc < 4; kc++)
                *(uint4*)&wf[cur ^ 1][kc] = *(const uint4*)&wn[kc * 16];
        }
        int di = tap / 3, dj = tap % 3;
        int cw = pg * 32 + (lane & 31) + dj;
        const unsigned short* tb = &ts[(di * 66 + cw) * 68 + half * 8];
#pragma unroll
        for (int kc = 0; kc < 4; kc++) {
            s16x8 bfv;
            ((uint2*)&bfv)[0] = *(const uint2*)&tb[kc * 16];
            ((uint2*)&bfv)[1] = *(const uint2*)&tb[kc * 16 + 4];
            acc = __builtin_amdgcn_mfma_f32_32x32x16_bf16(wf[cur][kc], bfv, acc, 0, 0, 0);
        }
    }

    int col = lane & 31;
    int pix = h * 64 + pg * 32 + col;
#pragma unroll
    for (int r = 0; r < 16; r++) {
        int o = o0 + (r & 3) + 8 * (r >> 2) + 4 * half;
        if (o < ENC)
            e_bf[((size_t)(n * ENC + o)) * HW_ + pix] = f2bf(acc[r] + be[o]);
    }
}

// ---------------- K3: softmax over 25 k, thread per pixel, packed bf16 out
// kern2b layout: [n][h][k][w][4 ij] ushort
__global__ __launch_bounds__(64) void k_softmax(const unsigned short* __restrict__ e_bf,
                                                unsigned short* __restrict__ kern2b) {
    int idx = blockIdx.x * 64 + threadIdx.x;  // 16384 total
    int hw  = idx & 4095;
    int n   = idx >> 12;
    int h   = hw >> 6, w = hw & 63;
    const unsigned short* ep = e_bf + (size_t)n * ENC * HW_ + hw;

    float v[25][4];
    float mx0 = -1e30f, mx1 = -1e30f, mx2 = -1e30f, mx3 = -1e30f;
#pragma unroll
    for (int k = 0; k < 25; k++) {
        v[k][0] = bf2f(ep[(size_t)(k * 4 + 0) * HW_]);
        v[k][1] = bf2f(ep[(size_t)(k * 4 + 1) * HW_]);
        v[k][2] = bf2f(ep[(size_t)(k * 4 + 2) * HW_]);
        v[k][3] = bf2f(ep[(size_t)(k * 4 + 3) * HW_]);
        mx0 = fmaxf(mx0, v[k][0]); mx1 = fmaxf(mx1, v[k][1]);
        mx2 = fmaxf(mx2, v[k][2]); mx3 = fmaxf(mx3, v[k][3]);
    }
    float s0 = 0.f, s1 = 0.f, s2 = 0.f, s3 = 0.f;
#pragma unroll
    for (int k = 0; k < 25; k++) {
        v[k][0] = __expf(v[k][0] - mx0); s0 += v[k][0];
        v[k][1] = __expf(v[k][1] - mx1); s1 += v[k][1];
        v[k][2] = __expf(v[k][2] - mx2); s2 += v[k][2];
        v[k][3] = __expf(v[k][3] - mx3); s3 += v[k][3];
    }
    float i0 = 1.f / s0, i1 = 1.f / s1, i2 = 1.f / s2, i3 = 1.f / s3;
    unsigned short* kp = kern2b + (((size_t)(n * 64 + h) * 25) * 64 + w) * 4;
#pragma unroll
    for (int k = 0; k < 25; k++) {
        ushort4 p;
        p.x = f2bf(v[k][0] * i0); p.y = f2bf(v[k][1] * i1);
        p.z = f2bf(v[k][2] * i2); p.w = f2bf(v[k][3] * i3);
        *(ushort4*)&kp[(size_t)k * 256] = p;
    }
}

// ---------------- K4: reassembly + pixel shuffle + bias
// block: (n, og of 32 o, 2 h-rows); thread: (w, 8 o), 32 acc; ys bf16 in LDS
__global__ __launch_bounds__(256) void k_reasm(const unsigned short* __restrict__ y1b,
                                               const unsigned short* __restrict__ kern2b,
                                               const float* __restrict__ bo,
                                               float* __restrict__ out) {
    int b  = blockIdx.x;           // 32 hs * 8 og * 4 n = 1024
    int hs = b & 31;
    int og = (b >> 5) & 7;
    int n  = b >> 8;
    int h0 = hs * 2;
    int o0 = og * 32;
    int tid = threadIdx.x;
    int w  = tid & 63;
    int ol = tid >> 6;             // 4 groups of 8 o

    __shared__ unsigned short ys[32 * 6 * 68];   // 26.1 KB: [(o*6+rr)*68 + c]

    const unsigned short* yb = y1b + ((size_t)(n * OC_ + o0)) * HW_;
    for (int l = tid; l < 32 * 6 * 68; l += 256) {
        int row = l / 68;          // o*6 + rr
        int c   = l - row * 68;
        int o   = row / 6, rr = row - o * 6;
        int gr  = h0 - 2 + rr, gc = c - 2;
        unsigned short v = 0;
        if (gr >= 0 && gr < H_ && gc >= 0 && gc < W_)
            v = yb[(size_t)o * HW_ + gr * W_ + gc];
        ys[l] = v;
    }
    __syncthreads();

    float bias[8];
#pragma unroll
    for (int oo = 0; oo < 8; oo++) bias[oo] = bo[o0 + ol * 8 + oo];

    for (int r = 0; r < 2; r++) {
        int h = h0 + r;
        float acc[8][4];
#pragma unroll
        for (int oo = 0; oo < 8; oo++)
#pragma unroll
            for (int q = 0; q < 4; q++) acc[oo][q] = 0.f;

        const unsigned short* kb = kern2b + (((size_t)(n * 64 + h) * 25) * 64 + w) * 4;
#pragma unroll
        for (int k = 0; k < 25; k++) {
            ushort4 kv4 = *(const ushort4*)&kb[(size_t)k * 256];
            float kv0 = bf2f(kv4.x), kv1 = bf2f(kv4.y);
            float kv2 = bf2f(kv4.z), kv3 = bf2f(kv4.w);
            int di = k / 5, dj = k % 5;
#pragma unroll
            for (int oo = 0; oo < 8; oo++) {
                float yv = bf2f(ys[((ol * 8 + oo) * 6 + r + di) * 68 + w + dj]);
                acc[oo][0] += kv0 * yv; acc[oo][1] += kv1 * yv;
                acc[oo][2] += kv2 * yv; acc[oo][3] += kv3 * yv;
            }
        }
#pragma unroll
        for (int oo = 0; oo < 8; oo++) {
            int o = o0 + ol * 8 + oo;
#pragma unroll
            for (int i = 0; i < 2; i++) {
                float2 v = make_float2(acc[oo][i * 2 + 0] + bias[oo],
                                       acc[oo][i * 2 + 1] + bias[oo]);
                *(float2*)&out[(((size_t)(n * OC_ + o)) * H2_ + (2 * h + i)) * W2_ + 2 * w] = v;
            }
        }
    }
}

extern "C" void kernel_launch(void* const* d_in, const int* in_sizes, int n_in,
                              void* d_out, int out_size, void* d_ws, size_t ws_size,
                              hipStream_t stream) {
    const float* x  = (const float*)d_in[0];
    const float* Wd = (const float*)d_in[1];
    const float* bd = (const float*)d_in[2];
    const float* We = (const float*)d_in[3];
    const float* be = (const float*)d_in[4];
    const float* Wo = (const float*)d_in[5];
    const float* bo = (const float*)d_in[6];
    float* out = (float*)d_out;

    // workspace (bytes), total 15.25 MB:
    //   y1b   [0,          8,388,608)   bf16 4x256x4096
    //   e_bf  [8,388,608,  11,665,408)  bf16 4x100x4096
    //   t2    [11,665,408, +2,097,152)  bf16 4x4096x64   (dead after k_enc)
    //   kern2b[11,665,408, +3,276,800)  bf16, time-aliases t2 (written after)
    //   Wcat  [14,942,208, +163,840)
    //   Web   [15,106,048, +147,456)
    char* wsb = (char*)d_ws;
    unsigned short* y1b    = (unsigned short*)wsb;
    unsigned short* e_bf   = (unsigned short*)(wsb + 8388608);
    unsigned short* t2     = (unsigned short*)(wsb + 11665408);
    unsigned short* kern2b = (unsigned short*)(wsb + 11665408);
    unsigned short* Wcat   = (unsigned short*)(wsb + 14942208);
    unsigned short* Web    = (unsigned short*)(wsb + 15106048);

    k_wcat   <<<320, 256, 0, stream>>>(Wo, Wd, Wcat);
    k_wprep  <<<288, 256, 0, stream>>>(We, Web);
    k_gemm   <<<1280, 256, 0, stream>>>(x, Wcat, bd, y1b, t2);
    k_enc    <<<1024, 128, 0, stream>>>(t2, Web, be, e_bf);
    k_softmax<<<256, 64, 0, stream>>>(e_bf, kern2b);
    k_reasm  <<<1024, 256, 0, stream>>>(y1b, kern2b, bo, out);
}

// Round 5
// 199.238 us; speedup vs baseline: 4.0460x; 1.0196x over previous
//
#include <hip/hip_runtime.h>

// Problem constants (CARAFE, delta=2, kup=5)
constexpr int N_  = 4;
constexpr int C_  = 256;
constexpr int H_  = 64;
constexpr int W_  = 64;
constexpr int Cm_ = 64;
constexpr int ENC = 100;
constexpr int OC_ = 256;
constexpr int HW_ = H_ * W_;       // 4096
constexpr int H2_ = 128, W2_ = 128;

typedef float  f32x16 __attribute__((ext_vector_type(16)));
typedef float  f32x2  __attribute__((ext_vector_type(2)));
typedef short  s16x8  __attribute__((ext_vector_type(8)));

__device__ inline unsigned short f2bf(float f) {
    unsigned int u = __float_as_uint(f);
    unsigned int r = u + 0x7FFFu + ((u >> 16) & 1u);  // RNE
    return (unsigned short)(r >> 16);
}
__device__ inline float bf2f(unsigned short s) {
    return __uint_as_float(((unsigned int)s) << 16);
}
__device__ inline void pk_fma(f32x2& d, f32x2 a, f32x2 b) {
    asm volatile("v_pk_fma_f32 %0, %1, %2, %0" : "+v"(d) : "v"(a), "v"(b));
}

// ---------------- prep: Wcat = [Wo(256,256); Wd(64,256)] -> bf16 [320][256]
__global__ __launch_bounds__(256) void k_wcat(const float* __restrict__ Wo,
                                              const float* __restrict__ Wd,
                                              unsigned short* __restrict__ Wcat) {
    int idx = blockIdx.x * 256 + threadIdx.x;     // 81920
    int row = idx >> 8, c = idx & 255;
    float v = (row < 256) ? Wo[idx] : Wd[(row - 256) * 256 + c];
    Wcat[idx] = f2bf(v);
}

// ---------------- prep: We (100,64,3,3) fp32 -> Web[tap][128 o][64 m] bf16
__global__ __launch_bounds__(256) void k_wprep(const float* __restrict__ We,
                                               unsigned short* __restrict__ Web) {
    int idx = blockIdx.x * 256 + threadIdx.x;     // 73728
    int tap = idx >> 13;
    int rem = idx & 8191;
    int o   = rem >> 6;
    int m   = rem & 63;
    Web[idx] = (o < ENC) ? f2bf(We[(o * Cm_ + m) * 9 + tap]) : (unsigned short)0;
}

// ---------------- K1: fused {y1 = Wo.x} and {t = Wd.x + bd} via MFMA
__global__ __launch_bounds__(256) void k_gemm(const float* __restrict__ x,
                                              const unsigned short* __restrict__ Wcat,
                                              const float* __restrict__ bd,
                                              unsigned short* __restrict__ y1b,
                                              unsigned short* __restrict__ t2) {
    int b   = blockIdx.x;              // 5 ot * 64 h * 4 n = 1280
    int ot  = b % 5;
    int rem = b / 5;
    int h   = rem & 63;
    int n   = rem >> 6;
    int o0  = ot * 64;
    int tid  = threadIdx.x;
    int lane = tid & 63;
    int wv   = tid >> 6;
    int og2  = wv & 1;
    int pg   = wv >> 1;

    __shared__ unsigned short xs[64 * 260];   // 33.3 KB

    const float* xr = x + (size_t)n * C_ * HW_ + h * 64;
    for (int idx = tid; idx < 4096; idx += 256) {
        int c  = idx >> 4;
        int ch = idx & 15;
        float4 v = *(const float4*)&xr[(size_t)c * HW_ + ch * 4];
        int p = ch * 4;
        xs[(p + 0) * 260 + c] = f2bf(v.x);
        xs[(p + 1) * 260 + c] = f2bf(v.y);
        xs[(p + 2) * 260 + c] = f2bf(v.z);
        xs[(p + 3) * 260 + c] = f2bf(v.w);
    }
    __syncthreads();

    f32x16 acc;
#pragma unroll
    for (int i = 0; i < 16; i++) acc[i] = 0.f;

    int oL   = og2 * 32 + (lane & 31);
    int half = lane >> 5;
    const unsigned short* wb = Wcat + ((size_t)(o0 + oL)) * C_ + half * 8;
    const unsigned short* tb = &xs[(pg * 32 + (lane & 31)) * 260 + half * 8];

    s16x8 wf[2];
    *(uint4*)&wf[0] = *(const uint4*)&wb[0];
    for (int kc = 0; kc < 16; kc++) {
        int cur = kc & 1;
        if (kc < 15)
            *(uint4*)&wf[cur ^ 1] = *(const uint4*)&wb[(kc + 1) * 16];
        s16x8 bfv;
        ((uint2*)&bfv)[0] = *(const uint2*)&tb[kc * 16];
        ((uint2*)&bfv)[1] = *(const uint2*)&tb[kc * 16 + 4];
        acc = __builtin_amdgcn_mfma_f32_32x32x16_bf16(wf[cur], bfv, acc, 0, 0, 0);
    }

    int col = lane & 31;
    int pix = h * 64 + pg * 32 + col;
    if (ot < 4) {
#pragma unroll
        for (int r = 0; r < 16; r++) {
            int o = o0 + og2 * 32 + (r & 3) + 8 * (r >> 2) + 4 * half;
            y1b[((size_t)(n * OC_ + o)) * HW_ + pix] = f2bf(acc[r]);
        }
    } else {
#pragma unroll
        for (int r = 0; r < 16; r++) {
            int m = og2 * 32 + (r & 3) + 8 * (r >> 2) + 4 * half;
            t2[((size_t)(n * HW_ + pix)) * 64 + m] = f2bf(acc[r] + bd[m]);
        }
    }
}

// ---------------- K2: fused 3x3 encoder conv (MFMA) + softmax -> kern2 fp32
// block: (n, h, 32-pixel half); 256 thr = 4 waves, wave = one 32-o tile
// kern2 layout: [n][h][k][ij][w] fp32
__global__ __launch_bounds__(256) void k_encsm(const unsigned short* __restrict__ t2,
                                               const unsigned short* __restrict__ Web,
                                               const float* __restrict__ be,
                                               float* __restrict__ kern2) {
    int b    = blockIdx.x;             // 2 ph * 64 h * 4 n = 512
    int ph   = b & 1;
    int h    = (b >> 1) & 63;
    int n    = b >> 7;
    int pix0 = ph * 32;
    int tid  = threadIdx.x;
    int lane = tid & 63;
    int wv   = tid >> 6;
    int o0   = wv * 32;

    __shared__ unsigned short ts[3 * 34 * 68];   // 13,872 B
    __shared__ float          es[32 * 105];      // 13,440 B

    // stage t rows h-1..h+1, cols pix0-1..pix0+32 (34), 64 m each
    for (int idx = tid; idx < 3 * 34 * 8; idx += 256) {
        int r   = idx / 272;
        int rem = idx - r * 272;
        int cw  = rem >> 3;
        int mc  = rem & 7;
        int gh  = h - 1 + r;
        int gw  = pix0 + cw - 1;
        uint2 lo = make_uint2(0u, 0u), hi = make_uint2(0u, 0u);
        if (gh >= 0 && gh < H_ && gw >= 0 && gw < W_) {
            uint4 v = *(const uint4*)&t2[((size_t)(n * HW_ + gh * W_ + gw)) * 64 + mc * 8];
            lo = make_uint2(v.x, v.y); hi = make_uint2(v.z, v.w);
        }
        int la = (r * 34 + cw) * 68 + mc * 8;
        *(uint2*)&ts[la]     = lo;
        *(uint2*)&ts[la + 4] = hi;
    }
    __syncthreads();

    f32x16 acc;
#pragma unroll
    for (int i = 0; i < 16; i++) acc[i] = 0.f;

    int oL   = lane & 31;
    int half = lane >> 5;
    const unsigned short* wb = Web + ((size_t)(o0 + oL)) * 64 + half * 8;

    s16x8 wf[2][4];
#pragma unroll
    for (int kc = 0; kc < 4; kc++)
        *(uint4*)&wf[0][kc] = *(const uint4*)&wb[kc * 16];

    for (int tap = 0; tap < 9; tap++) {
        int cur = tap & 1;
        if (tap < 8) {
            const unsigned short* wn = wb + (size_t)(tap + 1) * 128 * 64;
#pragma unroll
            for (int kc = 0; kc < 4; kc++)
                *(uint4*)&wf[cur ^ 1][kc] = *(const uint4*)&wn[kc * 16];
        }
        int di = tap / 3, dj = tap % 3;
        int cw = (lane & 31) + dj;
        const unsigned short* tb = &ts[(di * 34 + cw) * 68 + half * 8];
#pragma unroll
        for (int kc = 0; kc < 4; kc++) {
            s16x8 bfv;
            ((uint2*)&bfv)[0] = *(const uint2*)&tb[kc * 16];
            ((uint2*)&bfv)[1] = *(const uint2*)&tb[kc * 16 + 4];
            acc = __builtin_amdgcn_mfma_f32_32x32x16_bf16(wf[cur][kc], bfv, acc, 0, 0, 0);
        }
    }

    // scatter e into LDS [pix][o] (+bias), stride 105 = conflict-free
    int pixl = lane & 31;
#pragma unroll
    for (int r = 0; r < 16; r++) {
        int o = o0 + (r & 3) + 8 * (r >> 2) + 4 * half;
        if (o < ENC)
            es[pixl * 105 + o] = acc[r] + be[o];
    }
    __syncthreads();

    // softmax over k for (pix, ij); 128 active threads
    if (tid < 128) {
        int pix = tid & 31;
        int ij  = tid >> 5;
        float v[25];
        float mx = -1e30f;
#pragma unroll
        for (int k = 0; k < 25; k++) {
            v[k] = es[pix * 105 + k * 4 + ij];
            mx   = fmaxf(mx, v[k]);
        }
        float s = 0.f;
#pragma unroll
        for (int k = 0; k < 25; k++) {
            v[k] = __expf(v[k] - mx);
            s += v[k];
        }
        float inv = 1.0f / s;
        float* kp = kern2 + (size_t)(n * 64 + h) * 6400 + ij * 64 + pix0 + pix;
#pragma unroll
        for (int k = 0; k < 25; k++) kp[k * 256] = v[k] * inv;
    }
}

// ---------------- K3: reassembly + pixel shuffle + bias (pk_fma, w-pairs)
// block: (n, og of 16 o, 2 h-rows); thread: (w-pair, 2 o), 16 fp32 acc
__global__ __launch_bounds__(256) void k_reasm(const unsigned short* __restrict__ y1b,
                                               const float* __restrict__ kern2,
                                               const float* __restrict__ bo,
                                               float* __restrict__ out) {
    int b  = blockIdx.x;           // 32 hs * 16 og * 4 n = 2048
    int hs = b & 31;
    int og = (b >> 5) & 15;
    int n  = b >> 9;
    int h0 = hs * 2;
    int o0 = og * 16;
    int tid = threadIdx.x;
    int wp = tid & 31;             // w = 2*wp
    int ol = tid >> 5;             // 8 groups of 2 o

    __shared__ float ys[16 * 6 * 68];   // 26,112 B: [(o*6+rr)*68 + c]

    const unsigned short* yb = y1b + ((size_t)(n * OC_ + o0)) * HW_;
    for (int l = tid; l < 16 * 6 * 68; l += 256) {
        int row = l / 68;
        int c   = l - row * 68;
        int o   = row / 6, rr = row - o * 6;
        int gr  = h0 - 2 + rr, gc = c - 2;
        float v = 0.f;
        if (gr >= 0 && gr < H_ && gc >= 0 && gc < W_)
            v = bf2f(yb[(size_t)o * HW_ + gr * W_ + gc]);
        ys[l] = v;
    }
    __syncthreads();

    float bias[2];
#pragma unroll
    for (int o = 0; o < 2; o++) bias[o] = bo[o0 + ol * 2 + o];

    const float* kb = kern2 + (size_t)(n * 64) * 6400 + 2 * wp;
    for (int r = 0; r < 2; r++) {
        int h = h0 + r;
        f32x2 acc[2][4];
#pragma unroll
        for (int o = 0; o < 2; o++)
#pragma unroll
            for (int ij = 0; ij < 4; ij++) acc[o][ij] = (f32x2)(0.f);

        const float* kr = kb + (size_t)h * 6400;
#pragma unroll
        for (int k = 0; k < 25; k++) {
            f32x2 kv[4];
#pragma unroll
            for (int ij = 0; ij < 4; ij++)
                kv[ij] = *(const f32x2*)&kr[k * 256 + ij * 64];
            int di = k / 5, dj = k % 5;
#pragma unroll
            for (int o = 0; o < 2; o++) {
                const float* yr = &ys[((ol * 2 + o) * 6 + r + di) * 68 + 2 * wp + dj];
                f32x2 yv;
                yv.x = yr[0];
                yv.y = yr[1];
                pk_fma(acc[o][0], kv[0], yv);
                pk_fma(acc[o][1], kv[1], yv);
                pk_fma(acc[o][2], kv[2], yv);
                pk_fma(acc[o][3], kv[3], yv);
            }
        }
#pragma unroll
        for (int o = 0; o < 2; o++) {
            int oo = o0 + ol * 2 + o;
#pragma unroll
            for (int i = 0; i < 2; i++) {
                float4 v;
                v.x = acc[o][i * 2 + 0].x + bias[o];
                v.y = acc[o][i * 2 + 1].x + bias[o];
                v.z = acc[o][i * 2 + 0].y + bias[o];
                v.w = acc[o][i * 2 + 1].y + bias[o];
                *(float4*)&out[(((size_t)(n * OC_ + oo)) * H2_ + (2 * h + i)) * W2_ + 4 * wp] = v;
            }
        }
    }
}

extern "C" void kernel_launch(void* const* d_in, const int* in_sizes, int n_in,
                              void* d_out, int out_size, void* d_ws, size_t ws_size,
                              hipStream_t stream) {
    const float* x  = (const float*)d_in[0];
    const float* Wd = (const float*)d_in[1];
    const float* bd = (const float*)d_in[2];
    const float* We = (const float*)d_in[3];
    const float* be = (const float*)d_in[4];
    const float* Wo = (const float*)d_in[5];
    const float* bo = (const float*)d_in[6];
    float* out = (float*)d_out;

    // workspace (bytes), total 17,186,816 (< 17,301,504 proven in R1):
    //   y1b   [0,          8,388,608)   bf16 4x256x4096
    //   kern2 [8,388,608,  14,942,208)  fp32 4x64x25x4x64
    //         (Wcat bf16 163,840 B aliases its head; dead before k_encsm writes)
    //   t2    [14,942,208, 17,039,360)  bf16 4x4096x64
    //   Web   [17,039,360, 17,186,816)  bf16 9x128x64
    char* wsb = (char*)d_ws;
    unsigned short* y1b  = (unsigned short*)wsb;
    float*          kern2= (float*)(wsb + 8388608);
    unsigned short* Wcat = (unsigned short*)(wsb + 8388608);
    unsigned short* t2   = (unsigned short*)(wsb + 14942208);
    unsigned short* Web  = (unsigned short*)(wsb + 17039360);

    k_wcat  <<<320, 256, 0, stream>>>(Wo, Wd, Wcat);
    k_wprep <<<288, 256, 0, stream>>>(We, Web);
    k_gemm  <<<1280, 256, 0, stream>>>(x, Wcat, bd, y1b, t2);
    k_encsm <<<512, 256, 0, stream>>>(t2, Web, be, kern2);
    k_reasm <<<2048, 256, 0, stream>>>(y1b, kern2, bo, out);
}